// Round 5
// baseline (47.730 us; speedup 1.0000x reference)
//
#include <hip/hip_runtime.h>
#include <hip/hip_bf16.h>

// out[q] = min(|{r : dist(q,r) <= thr}|, 100) / 100   (top-k is unnecessary:
// any distance <= thr is among the 100 smallest unless count > 100, which clamps)
//
// Q=4096, R=16384, D=128. hit  <=>  dot(q,r) >= 0.5|q|^2 + (0.5|r|^2 - 0.5 thr^2)
// dot via bf16 MFMA; margin vs bf16 rounding ~100 (sq_dist ~120..400 vs 0.25).
//
// Structure: barrier-free, LDS-free. Each wave owns 64 query rows x a 512-ref
// segment; A-frags in registers; B-frags read directly from L1/L2 with a
// half-K software pipeline. The matrix pipe is the only shared resource.

#define DIM   128
#define ROWB  256              // bytes per bf16 row
#define WROWS 64               // query rows per wave
#define BM    256              // 4 waves stacked
#define BN    64               // ref cols per tile step
#define NSPLIT 32              // 32 segments x 512 refs

typedef __attribute__((ext_vector_type(8))) short short8;
typedef __attribute__((ext_vector_type(4))) float f32x4;

// ---------------- prep: bf16 cast, folded norms/bias, zero counts ----------
__global__ void prep_kernel(const float* __restrict__ qe, const float* __restrict__ re,
                            __hip_bfloat16* __restrict__ qb, __hip_bfloat16* __restrict__ rb,
                            float* __restrict__ qhalf, float* __restrict__ rbias,
                            float* __restrict__ counts, const float* __restrict__ thr_p,
                            int Q, int R) {
    const int wave = threadIdx.x >> 6;
    const int lane = threadIdx.x & 63;
    const int row = blockIdx.x * 4 + wave;
    if (row >= Q + R) return;
    const float* src;
    __hip_bfloat16* dst;
    if (row < Q) {
        src = qe + (size_t)row * DIM;
        dst = qb + (size_t)row * DIM;
        if (lane == 0) counts[row] = 0.0f;
    } else {
        src = re + (size_t)(row - Q) * DIM;
        dst = rb + (size_t)(row - Q) * DIM;
    }
    float2 v = ((const float2*)src)[lane];
    float s = v.x * v.x + v.y * v.y;
    __hip_bfloat162 b;
    b.x = __float2bfloat16(v.x);
    b.y = __float2bfloat16(v.y);
    ((__hip_bfloat162*)dst)[lane] = b;
    #pragma unroll
    for (int off = 32; off > 0; off >>= 1) s += __shfl_down(s, off);
    if (lane == 0) {
        if (row < Q) qhalf[row] = 0.5f * s;
        else {
            const float thr = *thr_p;
            rbias[row - Q] = (thr >= 0.0f) ? 0.5f * s - 0.5f * thr * thr : 1e30f;
        }
    }
}

// ---------------- main: barrier-free MFMA distance-count -------------------
__launch_bounds__(256, 2)
__global__ void dist_count_kernel(const __hip_bfloat16* __restrict__ qb,
                                  const __hip_bfloat16* __restrict__ rb,
                                  const float* __restrict__ qhalf,
                                  const float* __restrict__ rbias,
                                  float* __restrict__ counts,
                                  int Q, int R) {
    const int tid  = threadIdx.x;
    const int lane = tid & 63;
    const int wave = tid >> 6;

    const int seg  = R / NSPLIT;               // 512
    const int base = blockIdx.x * seg;
    const int NT   = seg / BN;                 // 8
    const int lr = lane & 15;
    const int lk = lane >> 4;
    const int qrow0 = blockIdx.y * BM + wave * WROWS;

    const char* qbc = (const char*)qb;
    const char* rbc = (const char*)rb;

    // ---- A fragments, full K=128, in registers (once) ----
    short8 a[4][4];                            // [ks][mi]
    #pragma unroll
    for (int ks = 0; ks < 4; ++ks)
        #pragma unroll
        for (int mi = 0; mi < 4; ++mi)
            a[ks][mi] = *(const short8*)(qbc + (size_t)(qrow0 + mi * 16 + lr) * ROWB + ks * 64 + lk * 16);

    // min of this lane's 16 query half-norms (for the screen)
    float minqh = 1e30f;
    #pragma unroll
    for (int mi = 0; mi < 4; ++mi)
        #pragma unroll
        for (int reg = 0; reg < 4; ++reg)
            minqh = fminf(minqh, qhalf[qrow0 + mi * 16 + lk * 4 + reg]);

    // B fragment pointers: one per ni (imm offsets cover ks/k-half)
    const char* p[4];
    #pragma unroll
    for (int ni = 0; ni < 4; ++ni)
        p[ni] = rbc + (size_t)(base + ni * 16 + lr) * ROWB + lk * 16;
    const float* rbp = rbias + base + lr;      // advances by BN per tile

    short8 b0[8], b1[8];                       // [ks2*4+ni], half-K each
    auto loadu = [&](short8* bb, int off) {
        #pragma unroll
        for (int ks2 = 0; ks2 < 2; ++ks2)
            #pragma unroll
            for (int ni = 0; ni < 4; ++ni)
                bb[ks2 * 4 + ni] = *(const short8*)(p[ni] + off + ks2 * 64);
    };

    loadu(b0, 0);                              // tile 0, k 0..63

    for (int t = 0; t < NT; ++t) {
        loadu(b1, 128);                        // tile t, k 64..127
        f32x4 acc[4][4] = {};

        #pragma unroll
        for (int ks = 0; ks < 2; ++ks)         // k-half 0
            #pragma unroll
            for (int mi = 0; mi < 4; ++mi)
                #pragma unroll
                for (int ni = 0; ni < 4; ++ni)
                    acc[mi][ni] = __builtin_amdgcn_mfma_f32_16x16x32_bf16(a[ks][mi], b0[ks * 4 + ni], acc[mi][ni], 0, 0, 0);

        #pragma unroll
        for (int ni = 0; ni < 4; ++ni) p[ni] += BN * ROWB;
        loadu(b0, 0);                          // prefetch tile t+1, k 0..63 (tail read is in-ws, unused)

        #pragma unroll
        for (int ks = 0; ks < 2; ++ks)         // k-half 1
            #pragma unroll
            for (int mi = 0; mi < 4; ++mi)
                #pragma unroll
                for (int ni = 0; ni < 4; ++ni)
                    acc[mi][ni] = __builtin_amdgcn_mfma_f32_16x16x32_bf16(a[ks + 2][mi], b1[ks * 4 + ni], acc[mi][ni], 0, 0, 0);

        // ---- screened epilogue ----
        float rh[4];
        #pragma unroll
        for (int ni = 0; ni < 4; ++ni) rh[ni] = rbp[ni * 16];
        const float minrh = fminf(fminf(rh[0], rh[1]), fminf(rh[2], rh[3]));

        f32x4 m4 = acc[0][0];
        #pragma unroll
        for (int mi = 0; mi < 4; ++mi)
            #pragma unroll
            for (int ni = 0; ni < 4; ++ni)
                if (mi || ni) {
                    #pragma unroll
                    for (int reg = 0; reg < 4; ++reg)
                        m4[reg] = fmaxf(m4[reg], acc[mi][ni][reg]);
                }
        const float mx = fmaxf(fmaxf(m4[0], m4[1]), fmaxf(m4[2], m4[3]));

        if (__any(mx >= minqh + minrh)) {      // rare slow path (generic-correct)
            #pragma unroll
            for (int mi = 0; mi < 4; ++mi)
                #pragma unroll
                for (int reg = 0; reg < 4; ++reg) {
                    const float qh = qhalf[qrow0 + mi * 16 + lk * 4 + reg];
                    float cnt = 0.0f;
                    #pragma unroll
                    for (int ni = 0; ni < 4; ++ni)
                        if (acc[mi][ni][reg] >= qh + rh[ni]) cnt += 1.0f;
                    cnt += __shfl_xor(cnt, 1);
                    cnt += __shfl_xor(cnt, 2);
                    cnt += __shfl_xor(cnt, 4);
                    cnt += __shfl_xor(cnt, 8);
                    if (lr == 0 && cnt != 0.0f)
                        atomicAdd(&counts[qrow0 + mi * 16 + lk * 4 + reg], cnt);
                }
        }
        rbp += BN;
    }
}

// ---------------- finalize ----------------
__global__ void finalize_kernel(const float* __restrict__ counts,
                                float* __restrict__ out, int Q, int R) {
    int q = blockIdx.x * blockDim.x + threadIdx.x;
    if (q < Q) {
        float k = (R < 100) ? (float)R : 100.0f;
        out[q] = fminf(counts[q], k) / k;
    }
}

extern "C" void kernel_launch(void* const* d_in, const int* in_sizes, int n_in,
                              void* d_out, int out_size, void* d_ws, size_t ws_size,
                              hipStream_t stream) {
    const float* qe  = (const float*)d_in[0];
    const float* re  = (const float*)d_in[1];
    const float* thr = (const float*)d_in[2];
    float* out = (float*)d_out;

    const int Q = in_sizes[0] / DIM;   // 4096
    const int R = in_sizes[1] / DIM;   // 16384

    char* ws = (char*)d_ws;
    __hip_bfloat16* qb = (__hip_bfloat16*)ws;
    __hip_bfloat16* rb = (__hip_bfloat16*)(ws + (size_t)Q * DIM * 2);
    float* qhalf  = (float*)(ws + (size_t)(Q + R) * DIM * 2);
    float* rbias  = qhalf + Q;
    float* counts = rbias + R;

    const int rows = Q + R;
    prep_kernel<<<(rows + 3) / 4, 256, 0, stream>>>(qe, re, qb, rb, qhalf, rbias, counts, thr, Q, R);

    dim3 grid(NSPLIT, Q / BM);   // (32, 16) = 512 blocks = 2/CU
    dist_count_kernel<<<grid, 256, 0, stream>>>(qb, rb, qhalf, rbias, counts, Q, R);

    finalize_kernel<<<(Q + 255) / 256, 256, 0, stream>>>(counts, out, Q, R);
}

// Round 6
// 33.489 us; speedup vs baseline: 1.4253x; 1.4253x over previous
//
#include <hip/hip_runtime.h>
#include <hip/hip_bf16.h>

// out[q] = min(|{r : dist(q,r) <= thr}|, 100) / 100   (top-k is unnecessary:
// any distance <= thr is among the 100 smallest unless count > 100, which clamps)
//
// Q=4096, R=16384, D=128. hit  <=>  dot(q,r) >= 0.5|q|^2 + (0.5|r|^2 - 0.5 thr^2)
// dot via bf16 32x32x16 MFMA. Structure: block = 512 queries x 256-ref segment;
// 4 waves, each wave owns 128 query rows (A in regs, K=128); B tiles of 32 refs
// staged via global_load_lds into a depth-3 LDS ring (counted vmcnt, T3/T4).
// FLOP per LDS byte is 4x R2's: LDS ~46% loaded, matrix pipe is the limiter.

#define DIM   128
#define ROWB  256              // bytes per bf16 row
#define BM    512              // queries per block (4 waves x 128)
#define BN    32               // refs per round
#define NSEG  64               // R/NSEG = 256 refs per block segment

typedef __attribute__((ext_vector_type(8)))  short short8;
typedef __attribute__((ext_vector_type(16))) float f32x16;

#define VMCNT(n) asm volatile("s_waitcnt vmcnt(" #n ")" ::: "memory")

// ---------------- prep: bf16 cast, folded norms/bias, zero counts ----------
__global__ void prep_kernel(const float* __restrict__ qe, const float* __restrict__ re,
                            __hip_bfloat16* __restrict__ qb, __hip_bfloat16* __restrict__ rb,
                            float* __restrict__ qhalf, float* __restrict__ rbias,
                            float* __restrict__ counts, const float* __restrict__ thr_p,
                            int Q, int R) {
    const int wave = threadIdx.x >> 6;
    const int lane = threadIdx.x & 63;
    const int row = blockIdx.x * 4 + wave;
    if (row >= Q + R) return;
    const float* src;
    __hip_bfloat16* dst;
    if (row < Q) {
        src = qe + (size_t)row * DIM;
        dst = qb + (size_t)row * DIM;
        if (lane == 0) counts[row] = 0.0f;
    } else {
        src = re + (size_t)(row - Q) * DIM;
        dst = rb + (size_t)(row - Q) * DIM;
    }
    float2 v = ((const float2*)src)[lane];
    float s = v.x * v.x + v.y * v.y;
    __hip_bfloat162 b;
    b.x = __float2bfloat16(v.x);
    b.y = __float2bfloat16(v.y);
    ((__hip_bfloat162*)dst)[lane] = b;
    #pragma unroll
    for (int off = 32; off > 0; off >>= 1) s += __shfl_down(s, off);
    if (lane == 0) {
        if (row < Q) qhalf[row] = 0.5f * s;
        else {
            const float thr = *thr_p;
            rbias[row - Q] = (thr >= 0.0f) ? 0.5f * s - 0.5f * thr * thr : 1e30f;
        }
    }
}

// ---------------- per-32-ref-tile min of rbias (for the screen) ------------
__global__ void tile_min_kernel(const float* __restrict__ rbias,
                                float* __restrict__ minrh, int R) {
    const int wave = threadIdx.x >> 6;
    const int lane = threadIdx.x & 63;
    const int l31 = lane & 31;
    const int tile = (blockIdx.x * 4 + wave) * 2 + (lane >> 5);   // 2 tiles/wave
    if (tile * BN >= R) return;
    float v = rbias[tile * BN + l31];
    #pragma unroll
    for (int off = 16; off > 0; off >>= 1) v = fminf(v, __shfl_xor(v, off));
    if (l31 == 0) minrh[tile] = v;
}

// ---------------- main: 32x32x16 MFMA, depth-3 ring, counted vmcnt ---------
__launch_bounds__(256, 2)
__global__ void dist_count_kernel(const __hip_bfloat16* __restrict__ qb,
                                  const __hip_bfloat16* __restrict__ rb,
                                  const float* __restrict__ qhalf,
                                  const float* __restrict__ rbias,
                                  const float* __restrict__ minrh,
                                  float* __restrict__ counts,
                                  int Q, int R) {
    __shared__ short Bs[3][BN * DIM];          // 3 x 8KB ring

    const int tid  = threadIdx.x;
    const int lane = tid & 63;
    const int wave = tid >> 6;
    const int l31  = lane & 31;
    const int lhi  = lane >> 5;

    const int seg  = R / NSEG;                 // 256
    const int base = blockIdx.x * seg;
    const int NT   = seg / BN;                 // 8
    const int qrow0 = blockIdx.y * BM + wave * 128;

    const char* qbc = (const char*)qb;
    const char* rbc = (const char*)rb;

    // stage one 32x128 bf16 tile (8KB): linear LDS dest, XOR-swizzle folded
    // into the GLOBAL source column (rule #21: both-sides-or-neither).
    auto stage = [&](int tt) {
        short* buf = Bs[tt % 3];
        #pragma unroll
        for (int j = 0; j < 2; ++j) {
            const int lds_byte = (wave * 2 + j) * 1024 + lane * 16;
            const int row = lds_byte >> 8;     // 0..31
            const int col = lds_byte & 255;
            const int src = (base + tt * BN + row) * ROWB + (col ^ ((row & 15) << 4));
            __builtin_amdgcn_global_load_lds(
                (const __attribute__((address_space(1))) unsigned int*)(rbc + src),
                (__attribute__((address_space(3))) unsigned int*)((char*)buf + lds_byte),
                16, 0, 0);
        }
    };

    // ---- A fragments: 128 query rows x K=128, in registers (once) ----
    // 32x32x16 A layout: row = lane&31, k = (lane>>5)*8 + j
    short8 a[8][4];                            // [ks][mi] : 128 VGPR
    #pragma unroll
    for (int ks = 0; ks < 8; ++ks)
        #pragma unroll
        for (int mi = 0; mi < 4; ++mi)
            a[ks][mi] = *(const short8*)(qbc + (size_t)(qrow0 + mi * 32 + l31) * ROWB
                                         + ks * 32 + lhi * 16);

    // wave-level min of the 128 query half-norms (conservative screen bound)
    float minqh;
    {
        float mq = fminf(qhalf[qrow0 + lane], qhalf[qrow0 + 64 + lane]);
        #pragma unroll
        for (int off = 32; off > 0; off >>= 1) mq = fminf(mq, __shfl_xor(mq, off));
        minqh = mq;
    }

    stage(0);
    stage(1);
    VMCNT(2);                                  // tile 0 resident (mine)

    for (int t = 0; t < NT; ++t) {
        __builtin_amdgcn_s_barrier();          // all waves' tile-t loads confirmed
        __builtin_amdgcn_sched_barrier(0);
        if (t + 2 < NT) stage(t + 2);          // slot (t+2)%3 free since round t-1

        const char* cur = (const char*)Bs[t % 3];
        f32x16 acc[4] = {};                    // [mi], ni=1

        __builtin_amdgcn_s_setprio(1);
        #pragma unroll
        for (int ks = 0; ks < 8; ++ks) {
            // B layout: row(ref) = lane&31, k = (lane>>5)*8 + j
            const int cb = (ks * 32 + lhi * 16) ^ ((l31 & 15) << 4);
            const short8 b = *(const short8*)(cur + l31 * ROWB + cb);
            #pragma unroll
            for (int mi = 0; mi < 4; ++mi)
                acc[mi] = __builtin_amdgcn_mfma_f32_32x32x16_bf16(a[ks][mi], b, acc[mi], 0, 0, 0);
        }
        __builtin_amdgcn_s_setprio(0);

        // ---- screened epilogue ----
        const float sc = minqh + minrh[base / BN + t];
        f32x16 m01 = acc[0], m23 = acc[2];
        #pragma unroll
        for (int r = 0; r < 16; ++r) {
            m01[r] = fmaxf(m01[r], acc[1][r]);
            m23[r] = fmaxf(m23[r], acc[3][r]);
        }
        float mx = fmaxf(m01[0], m23[0]);
        #pragma unroll
        for (int r = 1; r < 16; ++r) mx = fmaxf(mx, fmaxf(m01[r], m23[r]));

        if (__any(mx >= sc)) {                 // rare slow path (generic-correct)
            const int col = base + t * BN + l31;
            const float rbv = rbias[col];
            #pragma unroll
            for (int mi = 0; mi < 4; ++mi)
                #pragma unroll
                for (int reg = 0; reg < 16; ++reg) {
                    // 32x32 C layout: row = (reg&3) + 8*(reg>>2) + 4*(lane>>5)
                    const int row = qrow0 + mi * 32 + (reg & 3) + 8 * (reg >> 2) + 4 * lhi;
                    float cnt = (acc[mi][reg] >= qhalf[row] + rbv) ? 1.0f : 0.0f;
                    cnt += __shfl_xor(cnt, 1);
                    cnt += __shfl_xor(cnt, 2);
                    cnt += __shfl_xor(cnt, 4);
                    cnt += __shfl_xor(cnt, 8);
                    cnt += __shfl_xor(cnt, 16);
                    if (l31 == 0 && cnt != 0.0f)
                        atomicAdd(&counts[row], cnt);
                }
        }

        if (t + 2 < NT) { VMCNT(2); }          // tile t+1 resident; t+2 in flight
        else           { VMCNT(0); }
    }
}

// ---------------- finalize ----------------
__global__ void finalize_kernel(const float* __restrict__ counts,
                                float* __restrict__ out, int Q, int R) {
    int q = blockIdx.x * blockDim.x + threadIdx.x;
    if (q < Q) {
        float k = (R < 100) ? (float)R : 100.0f;
        out[q] = fminf(counts[q], k) / k;
    }
}

extern "C" void kernel_launch(void* const* d_in, const int* in_sizes, int n_in,
                              void* d_out, int out_size, void* d_ws, size_t ws_size,
                              hipStream_t stream) {
    const float* qe  = (const float*)d_in[0];
    const float* re  = (const float*)d_in[1];
    const float* thr = (const float*)d_in[2];
    float* out = (float*)d_out;

    const int Q = in_sizes[0] / DIM;   // 4096
    const int R = in_sizes[1] / DIM;   // 16384

    char* ws = (char*)d_ws;
    __hip_bfloat16* qb = (__hip_bfloat16*)ws;
    __hip_bfloat16* rb = (__hip_bfloat16*)(ws + (size_t)Q * DIM * 2);
    float* qhalf  = (float*)(ws + (size_t)(Q + R) * DIM * 2);
    float* rbias  = qhalf + Q;
    float* counts = rbias + R;
    float* minrh  = counts + Q;        // R/BN entries

    const int rows = Q + R;
    prep_kernel<<<(rows + 3) / 4, 256, 0, stream>>>(qe, re, qb, rb, qhalf, rbias, counts, thr, Q, R);

    const int ntiles = R / BN;         // 512
    tile_min_kernel<<<(ntiles + 7) / 8, 256, 0, stream>>>(rbias, minrh, R);

    dim3 grid(NSEG, Q / BM);           // (64, 8) = 512 blocks = 2/CU
    dist_count_kernel<<<grid, 256, 0, stream>>>(qb, rb, qhalf, rbias, minrh, counts, Q, R);

    finalize_kernel<<<(Q + 255) / 256, 256, 0, stream>>>(counts, out, Q, R);
}